// Round 1
// 504.393 us; speedup vs baseline: 1.0986x; 1.0986x over previous
//
#include <hip/hip_runtime.h>

#define S_LEN 920
#define DMODEL 1536
#define NH 4
#define HD 384
#define LREL 1839
#define BATCH 8
#define MTOT (BATCH * S_LEN)   // 7360
#define KPAD 960               // padded key-dim for PV gemm (Vt cols, PR cols)
#define PRLD 1840              // PR row stride in shorts (= SC row bytes/2)
#define NBH (BATCH * NH)       // 32

// ---- Q/K live inside d_out (shorts). Per 2-batch pair p, shorts
// [p*CHS, (p+1)*CHS) hold [Q(2p),K(2p),Q(2p+1),K(2p+1)]; chunk c's ctx output
// overwrites exactly its own batches' slabs AFTER scores consumed them.
#define CHS   5652480UL        // pair stride in shorts
#define BSLAB 2826240UL        // per-batch Q+K slab in shorts
#define KOFF  1413120UL        // K offset within batch slab (shorts)

// per-bh chunk buffer sizes (bytes)
#define TP_BH   1692800UL      // packed T: 920*920*2
#define SCPR_BH 3385600UL      // SC fp32 920*920*4; softmax overwrites in-place
#define CHBH    (TP_BH + SCPR_BH)   // 5,078,400
#define QKV_SCRATCH 36765696UL // Xb(22,609,920) + Wt(14,155,776)
#define EB_BYTES 1412352UL
#define VT_BYTES 23592960UL

typedef __attribute__((ext_vector_type(8))) short  s16x8;
typedef __attribute__((ext_vector_type(4))) short  s16x4;
typedef __attribute__((ext_vector_type(8))) __bf16 bf16x8;
typedef __attribute__((ext_vector_type(4))) float  f32x4;

__device__ __forceinline__ short f2b(float x) {
  unsigned u = __builtin_bit_cast(unsigned, x);
  unsigned r = (u + 0x7FFFu + ((u >> 16) & 1u)) >> 16;
  return (short)r;
}
__device__ __forceinline__ float b2f(short s) {
  unsigned u = ((unsigned)(unsigned short)s) << 16;
  return __builtin_bit_cast(float, u);
}

__device__ __forceinline__ void load_lds16(const short* g, short* lds) {
  __builtin_amdgcn_global_load_lds(
      (const __attribute__((address_space(1))) void*)g,
      (__attribute__((address_space(3))) void*)lds, 16, 0, 0);
}

__device__ __forceinline__ f32x4 mfma_bf16(s16x8 a, s16x8 b, f32x4 c) {
  return __builtin_amdgcn_mfma_f32_16x16x32_bf16(
      __builtin_bit_cast(bf16x8, a), __builtin_bit_cast(bf16x8, b), c, 0, 0, 0);
}

// ---------------------------------------------------------------------------
// 128x128 tile GEMM, C = A * B(NxK row-major)^T.  K multiple of 64.
// (used by k_gemm_T / k_gemm_ctx — unchanged this round)
// ---------------------------------------------------------------------------
__device__ __forceinline__ void gemm_core(short* As, short* Bs,
                                          const short* __restrict__ A, int ldA, int mClamp,
                                          const short* __restrict__ B, int ldB, int nClamp,
                                          int K, int m0, int n0, f32x4 acc[4][4]) {
  const int tid  = threadIdx.x;
  const int w    = tid >> 6;
  const int lane = tid & 63;
  const int lrow = lane >> 3;
  const int lcol = (lane & 7) * 8;
  const int lr   = lane & 15;
  const int lq   = lane >> 4;
  const int wm   = (w >> 1) * 64;
  const int wn   = (w & 1) * 64;

  const short* pa[4];
  const short* pb[4];
  short* la[4];
  short* lb[4];
#pragma unroll
  for (int i = 0; i < 4; ++i) {
    int row = w * 32 + i * 8 + lrow;
    int ra = m0 + row; if (ra > mClamp) ra = mClamp;
    int rb = n0 + row; if (rb > nClamp) rb = nClamp;
    pa[i] = A + (size_t)ra * ldA + lcol;
    pb[i] = B + (size_t)rb * ldB + lcol;
    la[i] = &As[(w * 32 + i * 8) * 64];
    lb[i] = &Bs[(w * 32 + i * 8) * 64];
  }

#pragma unroll
  for (int i = 0; i < 4; ++i)
#pragma unroll
    for (int j = 0; j < 4; ++j) acc[i][j] = (f32x4){0.f, 0.f, 0.f, 0.f};

  for (int k0 = 0; k0 < K; k0 += 64) {
#pragma unroll
    for (int i = 0; i < 4; ++i) {
      load_lds16(pa[i] + k0, la[i]);
      load_lds16(pb[i] + k0, lb[i]);
    }
    __syncthreads();
#pragma unroll
    for (int kk = 0; kk < 2; ++kk) {
      s16x8 af[4], bf[4];
#pragma unroll
      for (int f = 0; f < 4; ++f)
        af[f] = *(const s16x8*)&As[(wm + f * 16 + lr) * 64 + kk * 32 + lq * 8];
#pragma unroll
      for (int f = 0; f < 4; ++f)
        bf[f] = *(const s16x8*)&Bs[(wn + f * 16 + lr) * 64 + kk * 32 + lq * 8];
#pragma unroll
      for (int i = 0; i < 4; ++i)
#pragma unroll
        for (int j = 0; j < 4; ++j)
          acc[i][j] = mfma_bf16(af[i], bf[j], acc[i][j]);
    }
    __syncthreads();
  }
}

// ---------------------------------------------------------------------------
// 128x256 tile GEMM (used by k_gemm_scores — unchanged this round)
// ---------------------------------------------------------------------------
__device__ __forceinline__ void gemm_core256(short* As, short* Bs,
                                             const short* __restrict__ A, int ldA, int mClamp,
                                             const short* __restrict__ B, int ldB, int nClamp,
                                             int K, int m0, int n0, f32x4 acc[4][8]) {
  const int tid  = threadIdx.x;
  const int w    = tid >> 6;
  const int lane = tid & 63;
  const int lrow = lane >> 3;
  const int lcol = (lane & 7) * 8;
  const int lr   = lane & 15;
  const int lq   = lane >> 4;
  const int wm   = (w >> 1) * 64;
  const int wn   = (w & 1) * 128;

  const short* pa[4];
  short* la[4];
  const short* pb[8];
  short* lb[8];
#pragma unroll
  for (int i = 0; i < 4; ++i) {
    int row = w * 32 + i * 8 + lrow;
    int ra = m0 + row; if (ra > mClamp) ra = mClamp;
    pa[i] = A + (size_t)ra * ldA + lcol;
    la[i] = &As[(w * 32 + i * 8) * 64];
  }
#pragma unroll
  for (int i = 0; i < 8; ++i) {
    int row = w * 64 + i * 8 + lrow;
    int rb = n0 + row; if (rb > nClamp) rb = nClamp;
    pb[i] = B + (size_t)rb * ldB + lcol;
    lb[i] = &Bs[(w * 64 + i * 8) * 64];
  }

#pragma unroll
  for (int i = 0; i < 4; ++i)
#pragma unroll
    for (int j = 0; j < 8; ++j) acc[i][j] = (f32x4){0.f, 0.f, 0.f, 0.f};

  for (int k0 = 0; k0 < K; k0 += 64) {
#pragma unroll
    for (int i = 0; i < 4; ++i) load_lds16(pa[i] + k0, la[i]);
#pragma unroll
    for (int i = 0; i < 8; ++i) load_lds16(pb[i] + k0, lb[i]);
    __syncthreads();
#pragma unroll
    for (int kk = 0; kk < 2; ++kk) {
      s16x8 af[4], bf[8];
#pragma unroll
      for (int f = 0; f < 4; ++f)
        af[f] = *(const s16x8*)&As[(wm + f * 16 + lr) * 64 + kk * 32 + lq * 8];
#pragma unroll
      for (int f = 0; f < 8; ++f)
        bf[f] = *(const s16x8*)&Bs[(wn + f * 16 + lr) * 64 + kk * 32 + lq * 8];
#pragma unroll
      for (int i = 0; i < 4; ++i)
#pragma unroll
        for (int j = 0; j < 8; ++j)
          acc[i][j] = mfma_bf16(af[i], bf[j], acc[i][j]);
    }
    __syncthreads();
  }
}

// ---------------------------------------------------------------------------
__global__ void k_cast(const float* __restrict__ X, short* __restrict__ O, int n4) {
  int i = blockIdx.x * blockDim.x + threadIdx.x;
  if (i >= n4) return;
  float4 v = ((const float4*)X)[i];
  s16x4 o = {f2b(v.x), f2b(v.y), f2b(v.z), f2b(v.w)};
  *(s16x4*)&O[(size_t)i * 4] = o;
}

__global__ void k_transpose_w(const float* __restrict__ W0, const float* __restrict__ W1,
                              const float* __restrict__ W2, short* __restrict__ Wt) {
  const float* W = (blockIdx.z == 0) ? W0 : ((blockIdx.z == 1) ? W1 : W2);
  short* O = Wt + (size_t)blockIdx.z * DMODEL * DMODEL;
  __shared__ float t[32][33];
  int tx = threadIdx.x, ty = threadIdx.y;
  int n0 = blockIdx.x * 32, k0 = blockIdx.y * 32;
#pragma unroll
  for (int i = 0; i < 4; ++i)
    t[ty + i * 8][tx] = W[(size_t)(k0 + ty + i * 8) * DMODEL + n0 + tx];
  __syncthreads();
#pragma unroll
  for (int i = 0; i < 4; ++i)
    O[(size_t)(n0 + ty + i * 8) * DMODEL + k0 + tx] = f2b(t[tx][ty + i * 8]);
}

__global__ void k_zero_vtpad(short* __restrict__ Vt) {
  int idx = blockIdx.x * blockDim.x + threadIdx.x;
  if (idx >= NBH * HD * (KPAD - S_LEN)) return;
  int bhd = idx / (KPAD - S_LEN);
  int s = S_LEN + idx - bhd * (KPAD - S_LEN);
  Vt[(size_t)bhd * KPAD + s] = 0;
}

// ---------------------------------------------------------------------------
// QKV rewrite: 256x192 tile, BK=64, 512 threads (8 waves, 4m x 2n), double-
// buffered LDS with XOR-swizzle (T2), counted vmcnt(7) pipeline (T3/T4),
// phase-split MFMA clusters with setprio (T5).  Grid (232,1,3) = 696 blocks
// at 1 block/CU -> 91% round utilization (vs 68% before).
// ---------------------------------------------------------------------------
#define QKV_NT (DMODEL / 64)   // 24 K-tiles

// swizzled ds_read of one MFMA fragment.  Row stride 128 B; XOR 16B-slot
// bits with (row&7) -> 16 lanes spread over 8 slots (2-way = free).
__device__ __forceinline__ s16x8 qkv_frag(const short* base, int row, int kk, int lq) {
  int byte = (row << 7) + (kk << 6) + (lq << 4);
  byte ^= (row & 7) << 4;
  return *(const s16x8*)((const char*)base + byte);
}

__global__ __launch_bounds__(512, 2) void k_gemm_qkv(const short* __restrict__ Xb,
                                                     const short* __restrict__ Wt,
                                                     short* __restrict__ out16,
                                                     short* __restrict__ Vt) {
  __shared__ short smem[57344];                 // 112 KB: A0|B0|A1|B1; epilogue reuses
  short* const A0 = smem;                       // 256*64
  short* const B0 = smem + 16384;               // 192*64
  short* const A1 = smem + 28672;
  short* const B1 = smem + 45056;

  const int z = blockIdx.z;
  const int t = blockIdx.x;                     // [0,232)
  const int t2 = (t & 7) * 29 + (t >> 3);       // XCD-chunked, bijective (232 = 8*29)
  const int m0 = (t2 >> 3) * 256;
  const int n0 = (t2 & 7) * 192;

  const int tid = threadIdx.x, w = tid >> 6, lane = tid & 63;
  const int lr = lane & 15, lq = lane >> 4;
  const int wr = w >> 1, wc = w & 1;            // wave covers 64 rows x 96 cols

  const short* const Bg = Wt + (size_t)z * DMODEL * DMODEL;

  // stage pointers: 4 A-instrs + 3 B-instrs per wave per tile (7 vmcnt events).
  // LDS dest is linear (wave-uniform base + lane*16); the swizzle lives in the
  // per-lane GLOBAL source column (inverse == forward, XOR is an involution).
  const short* pa[4]; int la[4];
  const short* pb[3]; int lb[3];
  {
    const int rl = lane >> 3, c = lane & 7;
#pragma unroll
    for (int i = 0; i < 4; ++i) {
      int r = w * 32 + i * 8 + rl;              // LDS row [0,256)
      int ra = m0 + r; if (ra > MTOT - 1) ra = MTOT - 1;
      pa[i] = Xb + (size_t)ra * DMODEL + ((c ^ (r & 7)) * 8);
      la[i] = (w * 32 + i * 8) * 64;
    }
#pragma unroll
    for (int i = 0; i < 3; ++i) {
      int r = w * 24 + i * 8 + rl;              // LDS row [0,192)
      pb[i] = Bg + (size_t)(n0 + r) * DMODEL + ((c ^ (r & 7)) * 8);
      lb[i] = (w * 24 + i * 8) * 64;
    }
  }

  f32x4 acc[4][6];
#pragma unroll
  for (int i = 0; i < 4; ++i)
#pragma unroll
    for (int j = 0; j < 6; ++j) acc[i][j] = (f32x4){0.f, 0.f, 0.f, 0.f};

  // prologue: tile 0 -> buf0
#pragma unroll
  for (int i = 0; i < 4; ++i) load_lds16(pa[i], A0 + la[i]);
#pragma unroll
  for (int i = 0; i < 3; ++i) load_lds16(pb[i], B0 + lb[i]);

  for (int kt = 0; kt < QKV_NT; ++kt) {
    short* const Ab = (kt & 1) ? A1 : A0;
    short* const Bb = (kt & 1) ? B1 : B0;
    short* const An = (kt & 1) ? A0 : A1;
    short* const Bn = (kt & 1) ? B0 : B1;

    // issue next tile's stage FIRST (target buffer's readers finished at end
    // of tile kt-1 -> barrier-separated), then counted wait on THIS tile.
    if (kt + 1 < QKV_NT) {
      const int k0 = (kt + 1) * 64;
#pragma unroll
      for (int i = 0; i < 4; ++i) load_lds16(pa[i] + k0, An + la[i]);
#pragma unroll
      for (int i = 0; i < 3; ++i) load_lds16(pb[i] + k0, Bn + lb[i]);
      asm volatile("s_waitcnt vmcnt(7)" ::: "memory");   // tile kt landed; kt+1 in flight
    } else {
      asm volatile("s_waitcnt vmcnt(0)" ::: "memory");
    }
    __builtin_amdgcn_sched_barrier(0);
    __builtin_amdgcn_s_barrier();               // all waves' share of tile kt resident
    __builtin_amdgcn_sched_barrier(0);

    s16x8 a[4], bb[3];
    // ---- phase 0: kk=0, j=0..2 ----
#pragma unroll
    for (int f = 0; f < 4; ++f) a[f] = qkv_frag(Ab, wr * 64 + f * 16 + lr, 0, lq);
#pragma unroll
    for (int f = 0; f < 3; ++f) bb[f] = qkv_frag(Bb, wc * 96 + f * 16 + lr, 0, lq);
    __builtin_amdgcn_s_barrier();
    __builtin_amdgcn_s_setprio(1);
#pragma unroll
    for (int i = 0; i < 4; ++i)
#pragma unroll
      for (int j = 0; j < 3; ++j) acc[i][j] = mfma_bf16(a[i], bb[j], acc[i][j]);
    __builtin_amdgcn_s_setprio(0);
    __builtin_amdgcn_s_barrier();
    // ---- phase 1: kk=0, j=3..5 (reuse a) ----
#pragma unroll
    for (int f = 0; f < 3; ++f) bb[f] = qkv_frag(Bb, wc * 96 + (3 + f) * 16 + lr, 0, lq);
    __builtin_amdgcn_s_barrier();
    __builtin_amdgcn_s_setprio(1);
#pragma unroll
    for (int i = 0; i < 4; ++i)
#pragma unroll
      for (int j = 0; j < 3; ++j) acc[i][3 + j] = mfma_bf16(a[i], bb[j], acc[i][3 + j]);
    __builtin_amdgcn_s_setprio(0);
    __builtin_amdgcn_s_barrier();
    // ---- phase 2: kk=1, j=0..2 ----
#pragma unroll
    for (int f = 0; f < 4; ++f) a[f] = qkv_frag(Ab, wr * 64 + f * 16 + lr, 1, lq);
#pragma unroll
    for (int f = 0; f < 3; ++f) bb[f] = qkv_frag(Bb, wc * 96 + f * 16 + lr, 1, lq);
    __builtin_amdgcn_s_barrier();
    __builtin_amdgcn_s_setprio(1);
#pragma unroll
    for (int i = 0; i < 4; ++i)
#pragma unroll
      for (int j = 0; j < 3; ++j) acc[i][j] = mfma_bf16(a[i], bb[j], acc[i][j]);
    __builtin_amdgcn_s_setprio(0);
    __builtin_amdgcn_s_barrier();
    // ---- phase 3: kk=1, j=3..5 ----
#pragma unroll
    for (int f = 0; f < 3; ++f) bb[f] = qkv_frag(Bb, wc * 96 + (3 + f) * 16 + lr, 1, lq);
    __builtin_amdgcn_s_barrier();
    __builtin_amdgcn_s_setprio(1);
#pragma unroll
    for (int i = 0; i < 4; ++i)
#pragma unroll
      for (int j = 0; j < 3; ++j) acc[i][3 + j] = mfma_bf16(a[i], bb[j], acc[i][3 + j]);
    __builtin_amdgcn_s_setprio(0);
    __builtin_amdgcn_s_barrier();               // end of tile: buf kt free for overwrite
  }

  // ---- epilogue (LDS-routed, coalesced 16B stores) ----
  __syncthreads();
  const float inv = 0.05103103630798287f;       // 1/sqrt(384)
  if (z != 2) {
    short* T = smem;                            // [256][200] shorts
#pragma unroll
    for (int i = 0; i < 4; ++i)
#pragma unroll
      for (int j = 0; j < 6; ++j) {
        int ml = wr * 64 + i * 16 + lq * 4;
        int nl = wc * 96 + j * 16 + lr;
#pragma unroll
        for (int r = 0; r < 4; ++r) {
          float v = acc[i][j][r];
          T[(ml + r) * 200 + nl] = f2b(z == 0 ? v * inv : v);
        }
      }
    __syncthreads();
    for (int u = 0; u < 12; ++u) {
      int unit = u * 512 + tid;                 // 256 rows x 24 chunks of 16B
      int ml = unit / 24, c = unit - ml * 24;
      int m = m0 + ml;
      if (m < MTOT) {
        int b = m / S_LEN, s = m - b * S_LEN;
        short* dst = out16 + (size_t)(b >> 1) * CHS + (size_t)(b & 1) * BSLAB +
                     (z == 1 ? KOFF : 0UL) + (size_t)s * DMODEL + n0 + c * 8;
        *(s16x8*)dst = *(const s16x8*)&T[ml * 200 + c * 8];
      }
    }
  } else {
    short* T = smem;                            // [192][264] shorts (transposed)
#pragma unroll
    for (int i = 0; i < 4; ++i)
#pragma unroll
      for (int j = 0; j < 6; ++j) {
        int ml = wr * 64 + i * 16 + lq * 4;
        int nl = wc * 96 + j * 16 + lr;
#pragma unroll
        for (int r = 0; r < 4; ++r)
          T[nl * 264 + ml + r] = f2b(acc[i][j][r]);
      }
    __syncthreads();
    const int h = n0 / HD;                      // 192-col tile lies in one head
    const int d0 = n0 - h * HD;
    for (int u = 0; u < 12; ++u) {
      int unit = u * 512 + tid;                 // 192 rows x 32 chunks of 16B
      int nl = unit >> 5, c = unit & 31;
      int m = m0 + c * 8;
      if (m < MTOT) {
        int b = m / S_LEN, s = m - b * S_LEN;   // 920%8==0: chunk never crosses batch
        size_t row = (size_t)(b * NH + h) * HD + d0 + nl;
        *(s16x8*)&Vt[row * KPAD + s] = *(const s16x8*)&T[nl * 264 + c * 8];
      }
    }
  }
}

// T = Q @ E^T stored PACKED: Tp[m][n] = T[m][n - m + 919] (n = key index).
__global__ __launch_bounds__(256) void k_gemm_T(const short* __restrict__ out16,
                                                const short* __restrict__ Eb,
                                                short* __restrict__ Tp, int bh0) {
  __shared__ short smem[16384];
  const int z = blockIdx.z;
  const int bh = bh0 + z, b = bh >> 2, h = bh & 3;
  int t = blockIdx.x;
  int i_idx, j_idx;
  if (t < 7) { i_idx = t; j_idx = 6 - t; }
  else { int u = t - 7; int s = 7 + (u >> 3); i_idx = u & 7; j_idx = s - i_idx; }
  const int m0 = i_idx * 128, n0 = j_idx * 128;
  const short* A = out16 + (size_t)(b >> 1) * CHS + (size_t)(b & 1) * BSLAB + h * HD;
  f32x4 acc[4][4];
  gemm_core(smem, smem + 8192, A, DMODEL, S_LEN - 1, Eb, HD, LREL - 1, HD, m0, n0, acc);
  const int tid = threadIdx.x, w = tid >> 6, lane = tid & 63;
  const int lr = lane & 15, lq = lane >> 4;
  const int wm = (w >> 1) * 64, wn = (w & 1) * 64;
#pragma unroll
  for (int i = 0; i < 4; ++i)
#pragma unroll
    for (int j = 0; j < 4; ++j) {
      int l = n0 + wn + j * 16 + lr;           // rel-pos index
#pragma unroll
      for (int r = 0; r < 4; ++r) {
        int m = m0 + wm + i * 16 + lq * 4 + r;
        if (m < S_LEN) {
          int jp = l - (S_LEN - 1) + m;        // key index
          if (jp >= 0 && jp < S_LEN)
            Tp[((size_t)z * S_LEN + m) * S_LEN + jp] = f2b(acc[i][j][r]);
        }
      }
    }
}

// scores: 128x256 tiles, bias read is a plain coalesced Tp row.  Grid (8,4,CH).
__global__ __launch_bounds__(256, 2) void k_gemm_scores(const short* __restrict__ out16,
                                                        const short* __restrict__ Tp,
                                                        float* __restrict__ SCc, int bh0) {
  __shared__ short smem[24576];
  const int z = blockIdx.z;
  const int bh = bh0 + z, b = bh >> 2, h = bh & 3;
  const int m0 = blockIdx.x * 128, n0 = blockIdx.y * 256;
  const short* Qp = out16 + (size_t)(b >> 1) * CHS + (size_t)(b & 1) * BSLAB + h * HD;
  const short* Kp = Qp + KOFF;
  f32x4 acc[4][8];
  gemm_core256(smem, smem + 8192, Qp, DMODEL, S_LEN - 1, Kp, DMODEL, S_LEN - 1,
               HD, m0, n0, acc);
  const int tid = threadIdx.x, w = tid >> 6, lane = tid & 63;
  const int lr = lane & 15, lq = lane >> 4;
  const int wm = (w >> 1) * 64, wn = (w & 1) * 128;
#pragma unroll
  for (int i = 0; i < 4; ++i)
#pragma unroll
    for (int j = 0; j < 8; ++j) {
      int n = n0 + wn + j * 16 + lr;
#pragma unroll
      for (int r = 0; r < 4; ++r) {
        int m = m0 + wm + i * 16 + lq * 4 + r;
        if (m < S_LEN && n < S_LEN) {
          SCc[((size_t)z * S_LEN + m) * S_LEN + n] =
              acc[i][j][r] + b2f(Tp[((size_t)z * S_LEN + m) * S_LEN + n]);
        }
      }
    }
}

// softmax IN PLACE: reads 920 fp32 of a SC row, writes 960 bf16 probs into the
// first 1920 bytes of the same row (all reads precede writes via barriers).
__global__ __launch_bounds__(256) void k_softmax(float* __restrict__ SCc) {
  const int row = blockIdx.x;               // z*920 + q
  float* src = SCc + (size_t)row * S_LEN;
  short* dst = (short*)src;                 // stride PRLD row, in place
  const int tid = threadIdx.x, lane = tid & 63, wv = tid >> 6;
  float v[4];
#pragma unroll
  for (int i = 0; i < 4; ++i) {
    int k = i * 256 + tid;
    v[i] = (k < S_LEN) ? src[k] : -1e30f;
  }
  float mx = fmaxf(fmaxf(v[0], v[1]), fmaxf(v[2], v[3]));
  for (int off = 32; off; off >>= 1) mx = fmaxf(mx, __shfl_xor(mx, off));
  __shared__ float redm[4];
  __shared__ float reds[4];
  if (lane == 0) redm[wv] = mx;
  __syncthreads();
  mx = fmaxf(fmaxf(redm[0], redm[1]), fmaxf(redm[2], redm[3]));
  float e[4], s = 0.f;
#pragma unroll
  for (int i = 0; i < 4; ++i) { e[i] = __expf(v[i] - mx); s += e[i]; }
  for (int off = 32; off; off >>= 1) s += __shfl_xor(s, off);
  if (lane == 0) reds[wv] = s;
  __syncthreads();
  s = reds[0] + reds[1] + reds[2] + reds[3];
  float rs = 1.0f / s;
#pragma unroll
  for (int i = 0; i < 4; ++i) {
    int k = i * 256 + tid;
    if (k < KPAD) dst[k] = f2b(k < S_LEN ? e[i] * rs : 0.f);
  }
}

__global__ __launch_bounds__(256) void k_gemm_ctx(const short* __restrict__ PRc,
                                                  const short* __restrict__ Vt,
                                                  float* __restrict__ out, int bh0) {
  __shared__ short smem[16384];
  const int z = blockIdx.z;
  const int bh = bh0 + z, b = bh >> 2, h = bh & 3;
  const int m0 = blockIdx.x * 128, n0 = blockIdx.y * 128;
  const short* A = PRc + (size_t)z * S_LEN * PRLD;
  const short* Bt = Vt + (size_t)bh * HD * KPAD;
  f32x4 acc[4][4];
  gemm_core(smem, smem + 8192, A, PRLD, S_LEN - 1, Bt, KPAD, HD - 1, KPAD, m0, n0, acc);
  const int tid = threadIdx.x, w = tid >> 6, lane = tid & 63;
  const int lr = lane & 15, lq = lane >> 4;
  const int wm = (w >> 1) * 64, wn = (w & 1) * 64;
#pragma unroll
  for (int i = 0; i < 4; ++i)
#pragma unroll
    for (int j = 0; j < 4; ++j) {
      int n = n0 + wn + j * 16 + lr;
#pragma unroll
      for (int r = 0; r < 4; ++r) {
        int m = m0 + wm + i * 16 + lq * 4 + r;
        if (m < S_LEN)
          out[((size_t)(b * S_LEN) + m) * DMODEL + h * HD + n] = acc[i][j][r];
      }
    }
}

// ---------------------------------------------------------------------------
extern "C" void kernel_launch(void* const* d_in, const int* in_sizes, int n_in,
                              void* d_out, int out_size, void* d_ws, size_t ws_size,
                              hipStream_t stream) {
  const float* hs = (const float*)d_in[0];
  const float* wq = (const float*)d_in[1];
  const float* wk = (const float*)d_in[2];
  const float* wv = (const float*)d_in[3];
  const float* de = (const float*)d_in[4];
  char* ws = (char*)d_ws;

  int CH;
  if      (ws_size >= 32 * CHBH + EB_BYTES + VT_BYTES) CH = 32;   // 187.5 MB
  else if (ws_size >= 16 * CHBH + EB_BYTES + VT_BYTES) CH = 16;   // 106.3 MB
  else                                                  CH = 8;   //  65.6 MB
  size_t chunk_bytes = (size_t)CH * CHBH;
  size_t fixed_base = chunk_bytes > QKV_SCRATCH ? chunk_bytes : QKV_SCRATCH;

  short* Xb  = (short*)(ws + 0);
  short* Wt  = (short*)(ws + 22609920UL);
  short* Tp  = (short*)(ws + 0);                         // aliases Xb/Wt (dead)
  float* SCc = (float*)(ws + (size_t)CH * TP_BH);
  short* PRc = (short*)SCc;                              // softmax is in-place
  short* Eb  = (short*)(ws + fixed_base);
  short* Vt  = (short*)(ws + fixed_base + EB_BYTES);
  short* out16 = (short*)d_out;

  k_cast<<<(MTOT * DMODEL / 4 + 255) / 256, 256, 0, stream>>>(hs, Xb, MTOT * DMODEL / 4);
  k_cast<<<(LREL * HD / 4 + 255) / 256, 256, 0, stream>>>(de, Eb, LREL * HD / 4);
  k_transpose_w<<<dim3(48, 48, 3), dim3(32, 8, 1), 0, stream>>>(wq, wk, wv, Wt);
  k_zero_vtpad<<<(NBH * HD * (KPAD - S_LEN) + 255) / 256, 256, 0, stream>>>(Vt);

  k_gemm_qkv<<<dim3(232, 1, 3), 512, 0, stream>>>(Xb, Wt, out16, Vt);

  int NC = 32 / CH;
  for (int c = 0; c < NC; ++c) {
    int bh0 = c * CH;
    k_gemm_T<<<dim3(71, 1, CH), 256, 0, stream>>>(out16, Eb, Tp, bh0);
    k_gemm_scores<<<dim3(8, 4, CH), 256, 0, stream>>>(out16, Tp, SCc, bh0);
    k_softmax<<<CH * S_LEN, 256, 0, stream>>>(SCc);
    k_gemm_ctx<<<dim3(8, 3, CH), 256, 0, stream>>>(PRc, Vt, (float*)d_out, bh0);
  }
}